// Round 5
// baseline (164.243 us; speedup 1.0000x reference)
//
#include <hip/hip_runtime.h>

#define E_ 8
#define R_ 64
#define D_ 2048
#define BS_ 16384
#define SEG 64                               // int offset of per-expert segment lists
#define WS_ABF_OFF (1ull<<20)                // bf16 A (2MB) then B (2MB) at 1 MB
#define WS_NEED_FULL (WS_ABF_OFF + 4ull*1024*1024)
#define NTILE 512                            // 16-token tiles/expert (covers cnt<=8192, >70 sigma)

typedef __attribute__((ext_vector_type(8))) short short8;
typedef __attribute__((ext_vector_type(4))) short short4v;
typedef __attribute__((ext_vector_type(4))) float f32x4;

__device__ __forceinline__ unsigned short f2bf(float f){
  unsigned u = __float_as_uint(f);
  u += 0x7fffu + ((u >> 16) & 1u);           // RNE
  return (unsigned short)(u >> 16);
}
__device__ __forceinline__ short8 pack8(f32x4 a, f32x4 b){
  short8 r;
  r[0]=(short)f2bf(a[0]); r[1]=(short)f2bf(a[1]); r[2]=(short)f2bf(a[2]); r[3]=(short)f2bf(a[3]);
  r[4]=(short)f2bf(b[0]); r[5]=(short)f2bf(b[1]); r[6]=(short)f2bf(b[2]); r[7]=(short)f2bf(b[3]);
  return r;
}

// ---- prologue: scatter (blocks 0..63) + A,B fp32->bf16 conv (2048 blocks) ----
// ws ints: [0..8) cursors (end = counts) | [SEG + e*BS_ ...) token lists
__global__ void scatter_conv(const int* __restrict__ tidx, int* __restrict__ ws,
                             const float* __restrict__ Am, const float* __restrict__ Bm,
                             unsigned short* __restrict__ Abf){
  if (blockIdx.x >= 64){
    const int i = (blockIdx.x - 64)*256 + threadIdx.x;     // 4 elems each, 2M total
    const f32x4 v = (i < 262144) ? *(const f32x4*)(Am + (size_t)i*4)
                                 : *(const f32x4*)(Bm + (size_t)(i - 262144)*4);
    short4v a;
    a[0]=(short)f2bf(v[0]); a[1]=(short)f2bf(v[1]); a[2]=(short)f2bf(v[2]); a[3]=(short)f2bf(v[3]);
    *(short4v*)(Abf + (size_t)i*4) = a;                    // Bbf contiguous after Abf
    return;
  }
  __shared__ int lh[E_], lbase[E_], lrank[E_];
  const int t = threadIdx.x;
  if (t < E_){ lh[t] = 0; lrank[t] = 0; }
  __syncthreads();
  const int tok = blockIdx.x*256 + t;
  const int e = tidx[tok];
  atomicAdd(&lh[e], 1);
  __syncthreads();
  if (t < E_) lbase[t] = atomicAdd(&ws[t], lh[t]);   // device-scope
  __syncthreads();
  const int r = atomicAdd(&lrank[e], 1);
  ws[SEG + e*BS_ + lbase[e] + r] = tok;
}

// ---------------- Fused, barrier-free: out[tok] = B_e (A_e x[tok]) ----------------
// 16-token tiles, ~1024 active blocks (4/CU). NO LDS staging of x/A/B:
// A,B are 2+2 MB bf16 (L2-resident; e==blockIdx&7 pins each expert to one XCD's
// L2 under round-robin dispatch); x streams from HBM once with only intra-block
// reuse (L1/L2 absorbs). MFMA operands load straight from global; the compiler
// software-pipelines freely because there are exactly TWO barriers in the whole
// kernel (tokIds handoff, H handoff via 2 KB LDS). This deletes the 24-phase
// vmcnt(0)-drain chain that made the staged version latency-bound.
// Wave w owns r-quarter [w*16,w*16+16) in phase 1 and col-slice w*64 in phase 2.
__global__ __launch_bounds__(256, 4) void fused16(
    const float* __restrict__ x, const unsigned short* __restrict__ Abf,
    const int* __restrict__ ws, float* __restrict__ out)
{
  const int e    = blockIdx.x & 7;
  const int tile = blockIdx.x >> 3;            // 0..NTILE-1
  const int cnt  = ws[e];
  const int start = tile * 16;
  if (start >= cnt) return;
  const int valid = (cnt - start < 16) ? (cnt - start) : 16;
  const int* seg = ws + SEG + e*BS_;

  __shared__ int tokIds[16];
  __shared__ __align__(16) char pH[2048];      // H 16tok x 64r bf16, swizzled

  const int tid = threadIdx.x;
  if (tid < 16) tokIds[tid] = seg[start + (tid < valid ? tid : valid-1)];
  __syncthreads();                             // barrier #1

  const int lane = tid & 63, w = tid >> 6;     // 4 waves
  const int llo = lane & 15, lhi = lane >> 4;
  const int sw  = (llo & 7) << 4;

  // ---- phase 1: H = x A^T (per wave: 16 tok x 16 r, full K=2048) ----
  // A-frag (x): lane(llo,lhi) -> m=llo(token), k = c*128+kk*32+lhi*8+[0,8)
  // B-frag (A-matrix row w*16+llo): same k-slice
  const float* px = x + (size_t)tokIds[llo]*D_ + lhi*8;
  const unsigned short* pa = Abf + (size_t)(e*R_ + w*16 + llo)*D_ + lhi*8;
  f32x4 acc = {0.f,0.f,0.f,0.f};
  #pragma unroll 2
  for (int c = 0; c < 16; ++c){
    #pragma unroll
    for (int kk = 0; kk < 4; ++kk){
      const f32x4 v0 = *(const f32x4*)(px + c*128 + kk*32);
      const f32x4 v1 = *(const f32x4*)(px + c*128 + kk*32 + 4);
      const short8 b0 = *(const short8*)(pa + c*128 + kk*32);
      acc = __builtin_amdgcn_mfma_f32_16x16x32_bf16(pack8(v0, v1), b0, acc, 0,0,0);
    }
  }

  // ---- H -> pH (bf16, swizzled). C/D layout: token=(lane>>4)*4+i, r-col=llo ----
  #pragma unroll
  for (int i = 0; i < 4; ++i){
    const int hr = lhi*4 + i;                  // token 0..15
    *(unsigned short*)(pH + ((hr*128 + (w*16 + llo)*2) ^ ((hr & 7) << 4))) = f2bf(acc[i]);
  }
  __syncthreads();                             // barrier #2

  // H A-frags: m=llo(token), k(r) = lhi*8 (+[0,8)); aH1 covers r 32..63
  const short8 aH0 = *(const short8*)(pH + ((llo*128 + lhi*16) ^ sw));
  const short8 aH1 = *(const short8*)(pH + ((llo*128 + 64 + lhi*16) ^ sw));

  unsigned vmask = 0;
  int rowOff[4];
  #pragma unroll
  for (int i = 0; i < 4; ++i){
    const int r_ = lhi*4 + i;                  // output token row
    if (r_ < valid) vmask |= 1u << i;
    rowOff[i] = tokIds[r_ < valid ? r_ : 0]*D_ + llo;
  }

  // ---- phase 2: out = H B^T, B read direct from L2 (256 KB/expert, reused
  // by ~128 blocks). B-frag: n=llo(out-col), k(r)=lhi*8; b1 pairs aH1.
  const unsigned short* Bbf = Abf + E_*R_*D_;
  const unsigned short* pb = Bbf + (size_t)e*D_*R_ + (size_t)(w*64 + llo)*R_ + lhi*8;
  #pragma unroll 2
  for (int cg = 0; cg < 8; ++cg){
    #pragma unroll
    for (int nt = 0; nt < 4; ++nt){
      const short8 b0 = *(const short8*)(pb + cg*16384 + nt*1024);
      const short8 b1 = *(const short8*)(pb + cg*16384 + nt*1024 + 32);
      f32x4 o = {0.f,0.f,0.f,0.f};
      o = __builtin_amdgcn_mfma_f32_16x16x32_bf16(aH0, b0, o, 0,0,0);
      o = __builtin_amdgcn_mfma_f32_16x16x32_bf16(aH1, b1, o, 0,0,0);
      const int col = cg*256 + w*64 + nt*16;
      #pragma unroll
      for (int i = 0; i < 4; ++i)
        if (vmask & (1u << i))
          __builtin_nontemporal_store(o[i], &out[rowOff[i] + col]);
    }
  }
}

// ---------------- correctness-only fallback (tiny ws): exact fp32 ----------------
__global__ __launch_bounds__(256) void naive_kernel(
    const float* __restrict__ x, const float* __restrict__ Am,
    const float* __restrict__ Bm, const int* __restrict__ tidx,
    float* __restrict__ out)
{
  const int tok = blockIdx.x;
  const int e = tidx[tok];
  __shared__ float xs[D_];
  __shared__ float h[R_];
  const int tid = threadIdx.x;
  for (int i = tid; i < D_; i += 256) xs[i] = x[(size_t)tok*D_ + i];
  __syncthreads();
  if (tid < R_){
    float s = 0.f;
    const float* ar = Am + ((size_t)e*R_ + tid)*D_;
    for (int d = 0; d < D_; ++d) s += xs[d]*ar[d];
    h[tid] = s;
  }
  __syncthreads();
  for (int c = tid; c < D_; c += 256){
    float s = 0.f;
    const float* br = Bm + ((size_t)e*D_ + c)*R_;
    #pragma unroll
    for (int r = 0; r < R_; ++r) s += h[r]*br[r];
    out[(size_t)tok*D_ + c] = s;
  }
}

extern "C" void kernel_launch(void* const* d_in, const int* in_sizes, int n_in,
                              void* d_out, int out_size, void* d_ws, size_t ws_size,
                              hipStream_t stream){
  const float* x    = (const float*)d_in[0];
  const float* Am   = (const float*)d_in[1];
  const float* Bm   = (const float*)d_in[2];
  const int*   tidx = (const int*)d_in[3];
  float* out = (float*)d_out;
  int*   ws  = (int*)d_ws;
  unsigned short* Abf = (unsigned short*)((char*)d_ws + WS_ABF_OFF);

  if (ws_size >= WS_NEED_FULL){
    hipMemsetAsync(d_ws, 0, 32, stream);                    // zero 8 cursors
    scatter_conv<<<64 + 2048, 256, 0, stream>>>(tidx, ws, Am, Bm, Abf);
    fused16<<<8*NTILE, 256, 0, stream>>>(x, Abf, ws, out);  // 4096 blocks, ~1024 active
  } else {
    naive_kernel<<<BS_, 256, 0, stream>>>(x, Am, Bm, tidx, out);
  }
}

// Round 6
// 96.777 us; speedup vs baseline: 1.6971x; 1.6971x over previous
//
#include <hip/hip_runtime.h>

#define E_ 8
#define R_ 64
#define D_ 2048
#define BS_ 16384
#define SEG 64                               // int offset of per-expert segment lists
#define WS_ABF_OFF (1ull<<20)                // bf16 A (2MB) then B (2MB) at 1 MB
#define WS_NEED_FULL (WS_ABF_OFF + 4ull*1024*1024)
#define NT16 (BS_/16)                        // 1024 16-token tiles/expert: FULL coverage

typedef __attribute__((ext_vector_type(8))) short short8;
typedef __attribute__((ext_vector_type(4))) short short4v;
typedef __attribute__((ext_vector_type(4))) float f32x4;

__device__ __forceinline__ unsigned short f2bf(float f){
  unsigned u = __float_as_uint(f);
  u += 0x7fffu + ((u >> 16) & 1u);           // RNE
  return (unsigned short)(u >> 16);
}
__device__ __forceinline__ short8 pack8(f32x4 a, f32x4 b){
  short8 r;
  r[0]=(short)f2bf(a[0]); r[1]=(short)f2bf(a[1]); r[2]=(short)f2bf(a[2]); r[3]=(short)f2bf(a[3]);
  r[4]=(short)f2bf(b[0]); r[5]=(short)f2bf(b[1]); r[6]=(short)f2bf(b[2]); r[7]=(short)f2bf(b[3]);
  return r;
}
// async global->LDS DMA, 16B/lane. LDS dest = wave-uniform base + lane*16
// (linear); global src is PER-LANE (swizzle folded there). Counts in vmcnt;
// __syncthreads()'s implied vmcnt(0) is the completion wait (proven).
__device__ __forceinline__ void gload16(const void* g, void* l){
  __builtin_amdgcn_global_load_lds(
      (const __attribute__((address_space(1))) void*)g,
      (__attribute__((address_space(3))) void*)l, 16, 0, 0);
}

// ---- prologue: scatter (blocks 0..63) + A,B fp32->bf16 conv (2048 blocks) ----
// ws ints: [0..8) cursors (end = counts) | [SEG + e*BS_ ...) token lists
__global__ void scatter_conv(const int* __restrict__ tidx, int* __restrict__ ws,
                             const float* __restrict__ Am, const float* __restrict__ Bm,
                             unsigned short* __restrict__ Abf){
  if (blockIdx.x >= 64){
    const int i = (blockIdx.x - 64)*256 + threadIdx.x;     // 4 elems each, 2M total
    const f32x4 v = (i < 262144) ? *(const f32x4*)(Am + (size_t)i*4)
                                 : *(const f32x4*)(Bm + (size_t)(i - 262144)*4);
    short4v a;
    a[0]=(short)f2bf(v[0]); a[1]=(short)f2bf(v[1]); a[2]=(short)f2bf(v[2]); a[3]=(short)f2bf(v[3]);
    *(short4v*)(Abf + (size_t)i*4) = a;                    // Bbf contiguous after Abf
    return;
  }
  __shared__ int lh[E_], lbase[E_], lrank[E_];
  const int t = threadIdx.x;
  if (t < E_){ lh[t] = 0; lrank[t] = 0; }
  __syncthreads();
  const int tok = blockIdx.x*256 + t;
  const int e = tidx[tok];
  atomicAdd(&lh[e], 1);
  __syncthreads();
  if (t < E_) lbase[t] = atomicAdd(&ws[t], lh[t]);   // device-scope
  __syncthreads();
  const int r = atomicAdd(&lrank[e], 1);
  ws[SEG + e*BS_ + lbase[e] + r] = tok;
}

// ---------------- Fused: out[tok] = B_e (A_e x[tok]), 16-token tiles ----------------
// EXACT R0 proven structure (single-buffered, gload_lds DMA, 2 barriers/phase)
// with tile 32->16: ~1024 active blocks = 4/CU (was 2/CU) so four independent
// phase-chains per CU overlap each other's vmcnt(0) drains. LDS 34 KB:
// ph1 x 8K | A 16K | H 2K ; ph2 B 32K | H 2K. A/B staging doubles in aggregate
// but is L2-resident bf16 (2+2 MB) -> no extra HBM traffic.
// Wave w: ph1 computes 16tok x r[w*16,w*16+16); ph2 cols w*64..+64 per tile.
__global__ __launch_bounds__(256) void fused16s(
    const float* __restrict__ x, const unsigned short* __restrict__ Abf,
    const int* __restrict__ ws, float* __restrict__ out)
{
  const int e    = blockIdx.x & 7;
  const int tile = blockIdx.x >> 3;            // 0..NT16-1 (full coverage)
  const int cnt  = ws[e];
  const int start = tile * 16;
  if (start >= cnt) return;
  const int valid = (cnt - start < 16) ? (cnt - start) : 16;
  const int* seg = ws + SEG + e*BS_;

  __shared__ int tokIds[16];
  __shared__ __align__(16) char smem[34816];   // ph1: x8K|A16K ; ph2: B32K ; H at 32K

  const int tid = threadIdx.x;
  if (tid < 16) tokIds[tid] = seg[start + (tid < valid ? tid : valid-1)];
  __syncthreads();

  const int lane = tid & 63, w = tid >> 6;     // 4 waves
  // ---- phase-1 staging sources (per-lane, swizzle pre-folded) ----
  const char* xsrc[2]; const char* asrc[4];
  #pragma unroll
  for (int i = 0; i < 2; ++i){
    const int gi = w*2 + i;
    const int xrow = gi*2 + (lane >> 5);               // 2 rows per 1KB instr
    xsrc[i] = (const char*)(x + (size_t)tokIds[xrow]*D_)
              + (((lane & 31)*16) ^ ((xrow & 7) << 4));
  }
  #pragma unroll
  for (int i = 0; i < 4; ++i){
    const int gi = w*4 + i;
    const int arow = gi*4 + (lane >> 4);               // 4 rows per 1KB instr
    asrc[i] = (const char*)(Abf + ((size_t)e*R_ + arow)*D_)
              + (((lane & 15)*16) ^ ((arow & 7) << 4));
  }
  char* const xdst = smem;            //  8 KB
  char* const adst = smem + 8192;     // 16 KB
  char* const pH   = smem + 32768;    //  2 KB

  const int llo = lane & 15, lhi = lane >> 4;
  const int sw  = (llo & 7) << 4;              // == (row&7)<<4 for all rows used
  const int arow0 = w*16 + llo;                // wave's r-slice
  f32x4 acc = {0.f,0.f,0.f,0.f};

  for (int c = 0; c < 16; ++c){
    #pragma unroll
    for (int i = 0; i < 2; ++i)
      gload16(xsrc[i] + c*512, xdst + (w*2+i)*1024);
    #pragma unroll
    for (int i = 0; i < 4; ++i)
      gload16(asrc[i] + c*256, adst + (w*4+i)*1024);
    __syncthreads();                         // chunk landed (implied vmcnt(0))
    #pragma unroll
    for (int kk = 0; kk < 4; ++kk){
      const f32x4 v0 = *(const f32x4*)(xdst + llo*512 + ((kk*128 + lhi*32) ^ sw));
      const f32x4 v1 = *(const f32x4*)(xdst + llo*512 + ((kk*128 + lhi*32 + 16) ^ sw));
      const short8 af = pack8(v0, v1);
      const short8 b0 = *(const short8*)(adst + arow0*256 + ((kk*64 + lhi*16) ^ sw));
      acc = __builtin_amdgcn_mfma_f32_16x16x32_bf16(af, b0, acc, 0,0,0);
    }
    __syncthreads();                         // reads done before next DMA lands
  }

  // ---- H -> pH (bf16, swizzled). C/D layout: token=(lane>>4)*4+i, r=llo ----
  // (verified in R5's fused16)
  #pragma unroll
  for (int i = 0; i < 4; ++i){
    const int hr = lhi*4 + i;                  // token 0..15
    *(unsigned short*)(pH + ((hr*128 + (w*16 + llo)*2) ^ ((hr & 7) << 4))) = f2bf(acc[i]);
  }
  __syncthreads();

  // H A-frags: m=llo(token), k(r)=lhi*8; aH1 covers r 32..63 (verified in R5)
  const short8 aH0 = *(const short8*)(pH + ((llo*128 + lhi*16) ^ sw));
  const short8 aH1 = *(const short8*)(pH + ((llo*128 + 64 + lhi*16) ^ sw));

  unsigned vmask = 0;
  int rowOff[4];
  #pragma unroll
  for (int i = 0; i < 4; ++i){
    const int r_ = lhi*4 + i;                  // output token row
    if (r_ < valid) vmask |= 1u << i;
    rowOff[i] = tokIds[r_ < valid ? r_ : 0]*D_ + llo;
  }

  // ---- phase 2: per cg (8x) DMA a 256x64 bf16 B-tile, 8 MFMA/wave, NT stores ----
  const unsigned short* Bbf = Abf + E_*R_*D_;
  const char* bsrc = (const char*)Bbf + (size_t)e*D_*R_*2
                     + (size_t)(w*64 + (lane >> 3))*128
                     + (((lane & 7)*16) ^ (((lane >> 3) & 7) << 4));
  char* const pB = smem;                       // 32 KB, reuses x/A region

  for (int cg = 0; cg < 8; ++cg){
    #pragma unroll
    for (int i2 = 0; i2 < 8; ++i2)
      gload16(bsrc + cg*32768 + i2*1024, pB + (w*8+i2)*1024);
    __syncthreads();                           // B tile landed
    #pragma unroll
    for (int nt = 0; nt < 4; ++nt){
      const int rowL = w*64 + nt*16 + llo;     // (rowL&7) == (llo&7)
      const short8 b0 = *(const short8*)(pB + ((rowL*128 + lhi*16) ^ sw));
      const short8 b1 = *(const short8*)(pB + ((rowL*128 + 64 + lhi*16) ^ sw));
      f32x4 o = {0.f,0.f,0.f,0.f};
      o = __builtin_amdgcn_mfma_f32_16x16x32_bf16(aH0, b0, o, 0,0,0);
      o = __builtin_amdgcn_mfma_f32_16x16x32_bf16(aH1, b1, o, 0,0,0);
      const int col = cg*256 + w*64 + nt*16;
      #pragma unroll
      for (int i = 0; i < 4; ++i)
        if (vmask & (1u << i))
          __builtin_nontemporal_store(o[i], &out[rowOff[i] + col]);
    }
    __syncthreads();                           // reads done before next B DMA
  }
}

// ---------------- correctness-only fallback (tiny ws): exact fp32 ----------------
__global__ __launch_bounds__(256) void naive_kernel(
    const float* __restrict__ x, const float* __restrict__ Am,
    const float* __restrict__ Bm, const int* __restrict__ tidx,
    float* __restrict__ out)
{
  const int tok = blockIdx.x;
  const int e = tidx[tok];
  __shared__ float xs[D_];
  __shared__ float h[R_];
  const int tid = threadIdx.x;
  for (int i = tid; i < D_; i += 256) xs[i] = x[(size_t)tok*D_ + i];
  __syncthreads();
  if (tid < R_){
    float s = 0.f;
    const float* ar = Am + ((size_t)e*R_ + tid)*D_;
    for (int d = 0; d < D_; ++d) s += xs[d]*ar[d];
    h[tid] = s;
  }
  __syncthreads();
  for (int c = tid; c < D_; c += 256){
    float s = 0.f;
    const float* br = Bm + ((size_t)e*D_ + c)*R_;
    #pragma unroll
    for (int r = 0; r < R_; ++r) s += h[r]*br[r];
    out[(size_t)tok*D_ + c] = s;
  }
}

extern "C" void kernel_launch(void* const* d_in, const int* in_sizes, int n_in,
                              void* d_out, int out_size, void* d_ws, size_t ws_size,
                              hipStream_t stream){
  const float* x    = (const float*)d_in[0];
  const float* Am   = (const float*)d_in[1];
  const float* Bm   = (const float*)d_in[2];
  const int*   tidx = (const int*)d_in[3];
  float* out = (float*)d_out;
  int*   ws  = (int*)d_ws;
  unsigned short* Abf = (unsigned short*)((char*)d_ws + WS_ABF_OFF);

  if (ws_size >= WS_NEED_FULL){
    hipMemsetAsync(d_ws, 0, 32, stream);                    // zero 8 cursors
    scatter_conv<<<64 + 2048, 256, 0, stream>>>(tidx, ws, Am, Bm, Abf);
    fused16s<<<8*NT16, 256, 0, stream>>>(x, Abf, ws, out);  // 8192 blocks, ~1024 active
  } else {
    naive_kernel<<<BS_, 256, 0, stream>>>(x, Am, Bm, tidx, out);
  }
}